// Round 1
// baseline (630.398 us; speedup 1.0000x reference)
//
#include <hip/hip_runtime.h>
#include <hip/hip_bf16.h>
#include <stdint.h>

// FusedLinearCrossEntropyLoss on MI355X (gfx950)
// loss = mean_i( logsumexp_j(x_i . w_j + b_j) - (x_i . w_t(i) + b_t(i)) )
//
// Pipeline (all on `stream`):
//  1. cast_bf16_k : x, W fp32 -> bf16 in d_ws
//  2. xy_k        : target logit per row, fp32 (exact), d_ws
//  3. gemm_sumexp : 128x128-tile bf16 MFMA GEMM, epilogue = sum exp(logit+bias)
//                   per (row, col-block) -> partials[250][4096]  (no logits in HBM)
//  4. row_reduce  : per-row lse - x_y, block partial sums
//  5. finalize    : scalar loss

typedef float f4 __attribute__((ext_vector_type(4)));
typedef __bf16 bf8 __attribute__((ext_vector_type(8)));

#define GLD16(g, l) __builtin_amdgcn_global_load_lds(                      \
    (__attribute__((address_space(1))) void*)(g),                          \
    (__attribute__((address_space(3))) void*)(l), 16, 0, 0)

__device__ __forceinline__ unsigned short f2bf(float f) {
  unsigned u = __float_as_uint(f);
  u += 0x7fffu + ((u >> 16) & 1u);   // round-to-nearest-even
  return (unsigned short)(u >> 16);
}

__global__ __launch_bounds__(256) void cast_bf16_k(const float* __restrict__ in,
                                                   ushort4* __restrict__ out,
                                                   long n4) {
  long i = (long)blockIdx.x * blockDim.x + threadIdx.x;
  long stride = (long)gridDim.x * blockDim.x;
  const float4* in4 = (const float4*)in;
  for (; i < n4; i += stride) {
    float4 v = in4[i];
    ushort4 o;
    o.x = f2bf(v.x); o.y = f2bf(v.y); o.z = f2bf(v.z); o.w = f2bf(v.w);
    out[i] = o;
  }
}

// One block per row: x_y[row] = x[row] . W[safe_t] + bias[safe_t]  (fp32)
__global__ __launch_bounds__(256) void xy_k(const float* __restrict__ x,
                                            const float* __restrict__ w,
                                            const float* __restrict__ bias,
                                            const int* __restrict__ tgt,
                                            float* __restrict__ xy, int H, int V) {
  int row = blockIdx.x;
  int t = tgt[row];
  int st = min(max(t, 0), V - 1);
  const float4* xr = (const float4*)(x + (long)row * H);
  const float4* wr = (const float4*)(w + (long)st * H);
  float s = 0.f;
  int n4 = H >> 2;
  for (int i = threadIdx.x; i < n4; i += 256) {
    float4 a = xr[i], b = wr[i];
    s += a.x * b.x + a.y * b.y + a.z * b.z + a.w * b.w;
  }
  for (int off = 32; off; off >>= 1) s += __shfl_down(s, off, 64);
  __shared__ float sm[4];
  if ((threadIdx.x & 63) == 0) sm[threadIdx.x >> 6] = s;
  __syncthreads();
  if (threadIdx.x == 0) xy[row] = sm[0] + sm[1] + sm[2] + sm[3] + bias[st];
}

// 128x128 tile bf16 GEMM (BK=32), epilogue: partials[bn][row] = sum_cols exp(logit+bias)
__global__ __launch_bounds__(256)
void gemm_sumexp(const char* __restrict__ Xb, const char* __restrict__ Wb,
                 const float* __restrict__ bias, float* __restrict__ partials,
                 int H, int BT) {
  __shared__ __align__(16) char As[8192];   // 128 rows x 32 bf16 (64 B/row)
  __shared__ __align__(16) char Bs[8192];
  __shared__ float rowsum[2][128];

  const int tid = threadIdx.x;
  const int w = tid >> 6, lane = tid & 63;
  const int wr = w >> 1, wc = w & 1;
  const int quad = lane >> 4, l16 = lane & 15;
  const int m0 = blockIdx.y * 128, n0 = blockIdx.x * 128;

  const f4 fz = {0.f, 0.f, 0.f, 0.f};
  f4 acc[4][4];
#pragma unroll
  for (int i = 0; i < 4; i++)
#pragma unroll
    for (int j = 0; j < 4; j++) acc[i][j] = fz;

  const long Hb = (long)H * 2;  // row stride in bytes
  const int f0 = tid * 16;      // flat LDS byte offset, chunk 0
  const int f1 = f0 + 4096;     // chunk 1
  const int r0 = f0 >> 6, c0 = f0 & 63;
  const int r1 = f1 >> 6, c1 = f1 & 63;

  const char* gA0 = Xb + (long)(m0 + r0) * Hb + c0;
  const char* gA1 = Xb + (long)(m0 + r1) * Hb + c1;
  const char* gB0 = Wb + (long)(n0 + r0) * Hb + c0;
  const char* gB1 = Wb + (long)(n0 + r1) * Hb + c1;

  for (int k0 = 0; k0 < H; k0 += 32) {
    __syncthreads();  // previous compute done before overwriting LDS
    long kb = (long)k0 * 2;
    GLD16(gA0 + kb, As + f0);
    GLD16(gA1 + kb, As + f1);
    GLD16(gB0 + kb, Bs + f0);
    GLD16(gB1 + kb, Bs + f1);
    asm volatile("s_waitcnt vmcnt(0)" ::: "memory");
    __syncthreads();

    const bf8* Av = (const bf8*)As;
    const bf8* Bv = (const bf8*)Bs;
    bf8 a[4], b[4];
#pragma unroll
    for (int mi = 0; mi < 4; mi++) a[mi] = Av[(wr * 64 + mi * 16 + l16) * 4 + quad];
#pragma unroll
    for (int ni = 0; ni < 4; ni++) b[ni] = Bv[(wc * 64 + ni * 16 + l16) * 4 + quad];
#pragma unroll
    for (int mi = 0; mi < 4; mi++)
#pragma unroll
      for (int ni = 0; ni < 4; ni++)
        acc[mi][ni] =
            __builtin_amdgcn_mfma_f32_16x16x32_bf16(a[mi], b[ni], acc[mi][ni], 0, 0, 0);
  }

  // ---- epilogue: per-row sum of exp(logit + bias) ----
  float bv[4];
#pragma unroll
  for (int ni = 0; ni < 4; ni++) bv[ni] = bias[n0 + wc * 64 + ni * 16 + l16];

#pragma unroll
  for (int mi = 0; mi < 4; mi++) {
    float part[4] = {0.f, 0.f, 0.f, 0.f};
#pragma unroll
    for (int ni = 0; ni < 4; ni++) {
      f4 v = acc[mi][ni];
#pragma unroll
      for (int r = 0; r < 4; r++) part[r] += __expf(v[r] + bv[ni]);
    }
    // reduce across the 16 columns (lanes within 16-group)
#pragma unroll
    for (int off = 1; off < 16; off <<= 1)
#pragma unroll
      for (int r = 0; r < 4; r++) part[r] += __shfl_xor(part[r], off, 16);
    if (l16 == 0) {
#pragma unroll
      for (int r = 0; r < 4; r++)
        rowsum[wc][wr * 64 + mi * 16 + quad * 4 + r] = part[r];
    }
  }
  __syncthreads();
  if (tid < 128)
    partials[(long)blockIdx.x * BT + m0 + tid] = rowsum[0][tid] + rowsum[1][tid];
}

// per-row: lse - x_y ; block partial sums
__global__ __launch_bounds__(256)
void row_reduce(const float* __restrict__ partials, const float* __restrict__ xy,
                const int* __restrict__ tgt, float* __restrict__ bsum,
                float* __restrict__ bcnt, int BT, int nCB) {
  int row = blockIdx.x * 256 + threadIdx.x;
  float S = 0.f;
  for (int b = 0; b < nCB; b++) S += partials[(long)b * BT + row];
  int t = tgt[row];
  bool valid = (t != -100);
  float pr = valid ? (logf(S) - xy[row]) : 0.f;
  float c = valid ? 1.f : 0.f;
  for (int off = 32; off; off >>= 1) {
    pr += __shfl_down(pr, off, 64);
    c += __shfl_down(c, off, 64);
  }
  __shared__ float sp[4], sc[4];
  if ((threadIdx.x & 63) == 0) {
    sp[threadIdx.x >> 6] = pr;
    sc[threadIdx.x >> 6] = c;
  }
  __syncthreads();
  if (threadIdx.x == 0) {
    bsum[blockIdx.x] = sp[0] + sp[1] + sp[2] + sp[3];
    bcnt[blockIdx.x] = sc[0] + sc[1] + sc[2] + sc[3];
  }
}

__global__ void finalize(const float* __restrict__ bsum, const float* __restrict__ bcnt,
                         float* __restrict__ out, int nb) {
  float s = 0.f, c = 0.f;
  for (int i = threadIdx.x; i < nb; i += 64) { s += bsum[i]; c += bcnt[i]; }
  for (int off = 32; off; off >>= 1) {
    s += __shfl_down(s, off, 64);
    c += __shfl_down(c, off, 64);
  }
  if (threadIdx.x == 0) out[0] = s / c;
}

extern "C" void kernel_launch(void* const* d_in, const int* in_sizes, int n_in,
                              void* d_out, int out_size, void* d_ws, size_t ws_size,
                              hipStream_t stream) {
  const float* x = (const float*)d_in[0];
  const int* tgt = (const int*)d_in[1];
  const float* w = (const float*)d_in[2];
  const float* bias = (const float*)d_in[3];
  float* out = (float*)d_out;

  const int BT = in_sizes[1];            // 4096
  const int V = in_sizes[3];             // 32000
  const int H = in_sizes[0] / BT;        // 1024
  const int nCB = V / 128;               // 250 column blocks

  char* ws = (char*)d_ws;
  const long wb_bytes = (long)V * H * 2;
  const long xb_bytes = (long)BT * H * 2;
  char* Wb = ws;
  char* Xb = ws + wb_bytes;
  float* partials = (float*)(ws + wb_bytes + xb_bytes);
  float* xy = partials + (long)nCB * BT;
  float* bsum = xy + BT;
  float* bcnt = bsum + (BT / 256);

  cast_bf16_k<<<8192, 256, 0, stream>>>(w, (ushort4*)Wb, (long)V * H / 4);
  cast_bf16_k<<<1024, 256, 0, stream>>>(x, (ushort4*)Xb, (long)BT * H / 4);
  xy_k<<<BT, 256, 0, stream>>>(x, w, bias, tgt, xy, H, V);
  dim3 grid(nCB, BT / 128);
  gemm_sumexp<<<grid, 256, 0, stream>>>(Xb, Wb, bias, partials, H, BT);
  row_reduce<<<BT / 256, 256, 0, stream>>>(partials, xy, tgt, bsum, bcnt, BT, nCB);
  finalize<<<1, 64, 0, stream>>>(bsum, bcnt, out, BT / 256);
}

// Round 2
// 565.938 us; speedup vs baseline: 1.1139x; 1.1139x over previous
//
#include <hip/hip_runtime.h>
#include <hip/hip_bf16.h>
#include <stdint.h>

// FusedLinearCrossEntropyLoss on MI355X (gfx950)
// loss = mean_i( logsumexp_j(x_i . w_j + b_j) - (x_i . w_t(i) + b_t(i)) )
//
// R2: grid swapped for L2 W-reuse, XOR-swizzled LDS (conflict-free ds_read_b128),
//     BK=64 (half the barrier drains).

typedef float f4 __attribute__((ext_vector_type(4)));
typedef __bf16 bf8 __attribute__((ext_vector_type(8)));

#define GLD16(g, l) __builtin_amdgcn_global_load_lds(                      \
    (__attribute__((address_space(1))) void*)(g),                          \
    (__attribute__((address_space(3))) void*)(l), 16, 0, 0)

__device__ __forceinline__ unsigned short f2bf(float f) {
  unsigned u = __float_as_uint(f);
  u += 0x7fffu + ((u >> 16) & 1u);   // round-to-nearest-even
  return (unsigned short)(u >> 16);
}

__global__ __launch_bounds__(256) void cast_bf16_k(const float* __restrict__ in,
                                                   ushort4* __restrict__ out,
                                                   long n4) {
  long i = (long)blockIdx.x * blockDim.x + threadIdx.x;
  long stride = (long)gridDim.x * blockDim.x;
  const float4* in4 = (const float4*)in;
  for (; i < n4; i += stride) {
    float4 v = in4[i];
    ushort4 o;
    o.x = f2bf(v.x); o.y = f2bf(v.y); o.z = f2bf(v.z); o.w = f2bf(v.w);
    out[i] = o;
  }
}

// One block per row: x_y[row] = x[row] . W[safe_t] + bias[safe_t]  (fp32)
__global__ __launch_bounds__(256) void xy_k(const float* __restrict__ x,
                                            const float* __restrict__ w,
                                            const float* __restrict__ bias,
                                            const int* __restrict__ tgt,
                                            float* __restrict__ xy, int H, int V) {
  int row = blockIdx.x;
  int t = tgt[row];
  int st = min(max(t, 0), V - 1);
  const float4* xr = (const float4*)(x + (long)row * H);
  const float4* wr = (const float4*)(w + (long)st * H);
  float s = 0.f;
  int n4 = H >> 2;
  for (int i = threadIdx.x; i < n4; i += 256) {
    float4 a = xr[i], b = wr[i];
    s += a.x * b.x + a.y * b.y + a.z * b.z + a.w * b.w;
  }
  for (int off = 32; off; off >>= 1) s += __shfl_down(s, off, 64);
  __shared__ float sm[4];
  if ((threadIdx.x & 63) == 0) sm[threadIdx.x >> 6] = s;
  __syncthreads();
  if (threadIdx.x == 0) xy[row] = sm[0] + sm[1] + sm[2] + sm[3] + bias[st];
}

// 128x128 tile bf16 GEMM (BK=64), epilogue: partials[bn][row] = sum_cols exp(logit+bias)
// LDS layout: 128 rows x 128 B; row r's 16-B k-chunk q stored at position q^(r&7).
// -> ds_read_b128 bank-balanced; global side stays coalesced (8 lanes cover one
//    contiguous 128-B row, permuted within).
__global__ __launch_bounds__(256)
void gemm_sumexp(const char* __restrict__ Xb, const char* __restrict__ Wb,
                 const float* __restrict__ bias, float* __restrict__ partials,
                 int H, int BT) {
  __shared__ __align__(16) char As[16384];   // 128 rows x 64 bf16 (128 B/row)
  __shared__ __align__(16) char Bs[16384];
  __shared__ float rowsum[2][128];

  const int tid = threadIdx.x;
  const int w = tid >> 6, lane = tid & 63;
  const int wr = w >> 1, wc = w & 1;
  const int quad = lane >> 4, l16 = lane & 15;
  const int m0 = blockIdx.x * 128, n0 = blockIdx.y * 128;

  const f4 fz = {0.f, 0.f, 0.f, 0.f};
  f4 acc[4][4];
#pragma unroll
  for (int i = 0; i < 4; i++)
#pragma unroll
    for (int j = 0; j < 4; j++) acc[i][j] = fz;

  const long Hb = (long)H * 2;       // row stride in bytes
  const int sr = tid >> 3;           // staging row 0..31
  const int sp = tid & 7;            // LDS position within row
  const int sq = sp ^ (sr & 7);      // global k-chunk this thread fetches

  const char* gA = Xb + (long)(m0 + sr) * Hb + sq * 16;
  const char* gB = Wb + (long)(n0 + sr) * Hb + sq * 16;
  char* lA = As + tid * 16;
  char* lB = Bs + tid * 16;

  const int px0 = quad ^ (l16 & 7);        // h=0 read position
  const int px1 = (4 + quad) ^ (l16 & 7);  // h=1 read position

  for (int k0 = 0; k0 < H; k0 += 64) {
    __syncthreads();  // previous compute done before overwriting LDS
    long kb = (long)k0 * 2;
#pragma unroll
    for (int j = 0; j < 4; j++) {
      GLD16(gA + (long)j * 32 * Hb + kb, lA + j * 4096);
      GLD16(gB + (long)j * 32 * Hb + kb, lB + j * 4096);
    }
    asm volatile("s_waitcnt vmcnt(0)" ::: "memory");
    __syncthreads();

    const bf8* Av = (const bf8*)As;
    const bf8* Bv = (const bf8*)Bs;
#pragma unroll
    for (int h = 0; h < 2; h++) {
      const int px = h ? px1 : px0;
      bf8 a[4], b[4];
#pragma unroll
      for (int mi = 0; mi < 4; mi++) a[mi] = Av[(wr * 64 + mi * 16 + l16) * 8 + px];
#pragma unroll
      for (int ni = 0; ni < 4; ni++) b[ni] = Bv[(wc * 64 + ni * 16 + l16) * 8 + px];
#pragma unroll
      for (int mi = 0; mi < 4; mi++)
#pragma unroll
        for (int ni = 0; ni < 4; ni++)
          acc[mi][ni] =
              __builtin_amdgcn_mfma_f32_16x16x32_bf16(a[mi], b[ni], acc[mi][ni], 0, 0, 0);
    }
  }

  // ---- epilogue: per-row sum of exp(logit + bias) ----
  float bv[4];
#pragma unroll
  for (int ni = 0; ni < 4; ni++) bv[ni] = bias[n0 + wc * 64 + ni * 16 + l16];

#pragma unroll
  for (int mi = 0; mi < 4; mi++) {
    float part[4] = {0.f, 0.f, 0.f, 0.f};
#pragma unroll
    for (int ni = 0; ni < 4; ni++) {
      f4 v = acc[mi][ni];
#pragma unroll
      for (int r = 0; r < 4; r++) part[r] += __expf(v[r] + bv[ni]);
    }
#pragma unroll
    for (int off = 1; off < 16; off <<= 1)
#pragma unroll
      for (int r = 0; r < 4; r++) part[r] += __shfl_xor(part[r], off, 16);
    if (l16 == 0) {
#pragma unroll
      for (int r = 0; r < 4; r++)
        rowsum[wc][wr * 64 + mi * 16 + quad * 4 + r] = part[r];
    }
  }
  __syncthreads();
  if (tid < 128)
    partials[(long)blockIdx.y * BT + m0 + tid] = rowsum[0][tid] + rowsum[1][tid];
}

// per-row: lse - x_y ; block partial sums
__global__ __launch_bounds__(256)
void row_reduce(const float* __restrict__ partials, const float* __restrict__ xy,
                const int* __restrict__ tgt, float* __restrict__ bsum,
                float* __restrict__ bcnt, int BT, int nCB) {
  int row = blockIdx.x * 256 + threadIdx.x;
  float S = 0.f;
  for (int b = 0; b < nCB; b++) S += partials[(long)b * BT + row];
  int t = tgt[row];
  bool valid = (t != -100);
  float pr = valid ? (logf(S) - xy[row]) : 0.f;
  float c = valid ? 1.f : 0.f;
  for (int off = 32; off; off >>= 1) {
    pr += __shfl_down(pr, off, 64);
    c += __shfl_down(c, off, 64);
  }
  __shared__ float sp[4], sc[4];
  if ((threadIdx.x & 63) == 0) {
    sp[threadIdx.x >> 6] = pr;
    sc[threadIdx.x >> 6] = c;
  }
  __syncthreads();
  if (threadIdx.x == 0) {
    bsum[blockIdx.x] = sp[0] + sp[1] + sp[2] + sp[3];
    bcnt[blockIdx.x] = sc[0] + sc[1] + sc[2] + sc[3];
  }
}

__global__ void finalize(const float* __restrict__ bsum, const float* __restrict__ bcnt,
                         float* __restrict__ out, int nb) {
  float s = 0.f, c = 0.f;
  for (int i = threadIdx.x; i < nb; i += 64) { s += bsum[i]; c += bcnt[i]; }
  for (int off = 32; off; off >>= 1) {
    s += __shfl_down(s, off, 64);
    c += __shfl_down(c, off, 64);
  }
  if (threadIdx.x == 0) out[0] = s / c;
}

extern "C" void kernel_launch(void* const* d_in, const int* in_sizes, int n_in,
                              void* d_out, int out_size, void* d_ws, size_t ws_size,
                              hipStream_t stream) {
  const float* x = (const float*)d_in[0];
  const int* tgt = (const int*)d_in[1];
  const float* w = (const float*)d_in[2];
  const float* bias = (const float*)d_in[3];
  float* out = (float*)d_out;

  const int BT = in_sizes[1];            // 4096
  const int V = in_sizes[3];             // 32000
  const int H = in_sizes[0] / BT;        // 1024
  const int nCB = V / 128;               // 250 column blocks

  char* ws = (char*)d_ws;
  const long wb_bytes = (long)V * H * 2;
  const long xb_bytes = (long)BT * H * 2;
  char* Wb = ws;
  char* Xb = ws + wb_bytes;
  float* partials = (float*)(ws + wb_bytes + xb_bytes);
  float* xy = partials + (long)nCB * BT;
  float* bsum = xy + BT;
  float* bcnt = bsum + (BT / 256);

  cast_bf16_k<<<8192, 256, 0, stream>>>(w, (ushort4*)Wb, (long)V * H / 4);
  cast_bf16_k<<<1024, 256, 0, stream>>>(x, (ushort4*)Xb, (long)BT * H / 4);
  xy_k<<<BT, 256, 0, stream>>>(x, w, bias, tgt, xy, H, V);
  // grid.x = row-blocks (fast-varying) so consecutive blocks share the W tile in L2
  dim3 grid(BT / 128, nCB);
  gemm_sumexp<<<grid, 256, 0, stream>>>(Xb, Wb, bias, partials, H, BT);
  row_reduce<<<BT / 256, 256, 0, stream>>>(partials, xy, tgt, bsum, bcnt, BT, nCB);
  finalize<<<1, 64, 0, stream>>>(bsum, bcnt, out, BT / 256);
}

// Round 3
// 465.391 us; speedup vs baseline: 1.3546x; 1.2160x over previous
//
#include <hip/hip_runtime.h>
#include <hip/hip_bf16.h>
#include <stdint.h>

// FusedLinearCrossEntropyLoss on MI355X (gfx950)
// loss = mean_i( logsumexp_j(x_i . w_j + b_j) - (x_i . w_t(i) + b_t(i)) )
//
// R3: GEMM ported to MX-fp8 (mfma_scale_f32_32x32x64_f8f6f4, identity scales)
//     at 2x the bf16 MFMA rate. BK=128 (128 fp8 bytes/row) keeps R2's verified
//     conflict-free XOR-swizzled LDS layout. Casts emit fp8 via v_cvt_pk_fp8_f32.
//     x_y (target logit) stays exact fp32 so quantization only perturbs the lse.

typedef float f16v __attribute__((ext_vector_type(16)));
typedef int v8i __attribute__((ext_vector_type(8)));

#define GLD16(g, l) __builtin_amdgcn_global_load_lds(                      \
    (__attribute__((address_space(1))) void*)(g),                          \
    (__attribute__((address_space(3))) void*)(l), 16, 0, 0)

__device__ __forceinline__ unsigned pk_fp8(float4 v) {
  int w = 0;
  w = __builtin_amdgcn_cvt_pk_fp8_f32(v.x, v.y, w, false);  // bytes 0,1
  w = __builtin_amdgcn_cvt_pk_fp8_f32(v.z, v.w, w, true);   // bytes 2,3
  return (unsigned)w;
}

// fp32 -> fp8 e4m3 (OCP), 16 elements per thread
__global__ __launch_bounds__(256) void cast_fp8_k(const float4* __restrict__ in,
                                                  uint4* __restrict__ out, long n16) {
  long i = (long)blockIdx.x * blockDim.x + threadIdx.x;
  long stride = (long)gridDim.x * blockDim.x;
  for (; i < n16; i += stride) {
    float4 v0 = in[i * 4 + 0], v1 = in[i * 4 + 1];
    float4 v2 = in[i * 4 + 2], v3 = in[i * 4 + 3];
    uint4 o;
    o.x = pk_fp8(v0); o.y = pk_fp8(v1); o.z = pk_fp8(v2); o.w = pk_fp8(v3);
    out[i] = o;
  }
}

// One block per row: x_y[row] = x[row] . W[safe_t] + bias[safe_t]  (fp32, exact)
__global__ __launch_bounds__(256) void xy_k(const float* __restrict__ x,
                                            const float* __restrict__ w,
                                            const float* __restrict__ bias,
                                            const int* __restrict__ tgt,
                                            float* __restrict__ xy, int H, int V) {
  int row = blockIdx.x;
  int t = tgt[row];
  int st = min(max(t, 0), V - 1);
  const float4* xr = (const float4*)(x + (long)row * H);
  const float4* wr = (const float4*)(w + (long)st * H);
  float s = 0.f;
  int n4 = H >> 2;
  for (int i = threadIdx.x; i < n4; i += 256) {
    float4 a = xr[i], b = wr[i];
    s += a.x * b.x + a.y * b.y + a.z * b.z + a.w * b.w;
  }
  for (int off = 32; off; off >>= 1) s += __shfl_down(s, off, 64);
  __shared__ float sm[4];
  if ((threadIdx.x & 63) == 0) sm[threadIdx.x >> 6] = s;
  __syncthreads();
  if (threadIdx.x == 0) xy[row] = sm[0] + sm[1] + sm[2] + sm[3] + bias[st];
}

// 128x128 tile fp8 GEMM (BK=128), 4 waves in 2x2, each wave a 2x2 grid of
// 32x32x64 scaled MFMAs. LDS rows are 128 B; row r's 16-B chunk c lives at
// position c^(r&7) (R2-verified conflict-free for both staging and ds_read).
// Epilogue: partials[bn][row] = sum_cols exp(logit + bias), logits never hit HBM.
__global__ __launch_bounds__(256)
void gemm_sumexp(const char* __restrict__ Xb, const char* __restrict__ Wb,
                 const float* __restrict__ bias, float* __restrict__ partials,
                 int H, int BT) {
  __shared__ __align__(16) char As[16384];   // 128 rows x 128 fp8
  __shared__ __align__(16) char Bs[16384];
  __shared__ float rowsum[2][128];

  const int tid = threadIdx.x;
  const int w = tid >> 6, lane = tid & 63;
  const int wr = w >> 1, wc = w & 1;
  const int l32 = lane & 31, kh = lane >> 5;
  const int m0 = blockIdx.x * 128, n0 = blockIdx.y * 128;

  f16v acc[2][2];
#pragma unroll
  for (int mi = 0; mi < 2; mi++)
#pragma unroll
    for (int ni = 0; ni < 2; ni++)
#pragma unroll
      for (int r = 0; r < 16; r++) acc[mi][ni][r] = 0.f;

  // staging: thread t covers row sr, LDS position sp, global chunk sq = sp^(sr&7)
  const int sr = tid >> 3, sp = tid & 7, sq = sp ^ (sr & 7);
  const char* gA = Xb + (long)(m0 + sr) * H + sq * 16;
  const char* gB = Wb + (long)(n0 + sr) * H + sq * 16;
  char* lA = As + tid * 16;
  char* lB = Bs + tid * 16;

  const int rx = l32 & 7;                      // row-xor for fragment reads
  const int abase = (wr * 64 + l32) * 128;     // mi adds +4096
  const int bbase = (wc * 64 + l32) * 128;     // ni adds +4096

  for (int k0 = 0; k0 < H; k0 += 128) {
    __syncthreads();  // previous compute done before overwriting LDS
#pragma unroll
    for (int j = 0; j < 4; j++) {
      GLD16(gA + (long)j * 32 * H + k0, lA + j * 4096);
      GLD16(gB + (long)j * 32 * H + k0, lB + j * 4096);
    }
    asm volatile("s_waitcnt vmcnt(0)" ::: "memory");
    __syncthreads();

#pragma unroll
    for (int s = 0; s < 2; s++) {              // two K=64 sub-steps
      const int c0 = s * 4 + kh * 2;           // lane's first 16-B k-chunk
      const int o0 = (c0 ^ rx) * 16;
      const int o1 = ((c0 + 1) ^ rx) * 16;
      v8i a[2], b[2];
#pragma unroll
      for (int mi = 0; mi < 2; mi++) {
        int4 lo = *(const int4*)(As + abase + mi * 4096 + o0);
        int4 hi = *(const int4*)(As + abase + mi * 4096 + o1);
        v8i t;
        t[0] = lo.x; t[1] = lo.y; t[2] = lo.z; t[3] = lo.w;
        t[4] = hi.x; t[5] = hi.y; t[6] = hi.z; t[7] = hi.w;
        a[mi] = t;
      }
#pragma unroll
      for (int ni = 0; ni < 2; ni++) {
        int4 lo = *(const int4*)(Bs + bbase + ni * 4096 + o0);
        int4 hi = *(const int4*)(Bs + bbase + ni * 4096 + o1);
        v8i t;
        t[0] = lo.x; t[1] = lo.y; t[2] = lo.z; t[3] = lo.w;
        t[4] = hi.x; t[5] = hi.y; t[6] = hi.z; t[7] = hi.w;
        b[ni] = t;
      }
#pragma unroll
      for (int mi = 0; mi < 2; mi++)
#pragma unroll
        for (int ni = 0; ni < 2; ni++)
          acc[mi][ni] = __builtin_amdgcn_mfma_scale_f32_32x32x64_f8f6f4(
              a[mi], b[ni], acc[mi][ni], 0 /*A=fp8*/, 0 /*B=fp8*/,
              0, 127 /*scale_a = 1.0*/, 0, 127 /*scale_b = 1.0*/);
    }
  }

  // ---- epilogue: per-row sum of exp(logit + bias) ----
  // C/D 32x32 layout: col = lane&31, row = (reg&3) + 8*(reg>>2) + 4*(lane>>5)
  float bv[2];
  bv[0] = bias[n0 + wc * 64 + l32];
  bv[1] = bias[n0 + wc * 64 + 32 + l32];

#pragma unroll
  for (int mi = 0; mi < 2; mi++) {
    float p[16];
#pragma unroll
    for (int r = 0; r < 16; r++) p[r] = 0.f;
#pragma unroll
    for (int ni = 0; ni < 2; ni++)
#pragma unroll
      for (int r = 0; r < 16; r++) p[r] += __expf(acc[mi][ni][r] + bv[ni]);
    // reduce across the 32 columns (lanes within each 32-group)
#pragma unroll
    for (int off = 1; off < 32; off <<= 1)
#pragma unroll
      for (int r = 0; r < 16; r++) p[r] += __shfl_xor(p[r], off, 32);
    if (l32 == 0) {
#pragma unroll
      for (int r = 0; r < 16; r++)
        rowsum[wc][wr * 64 + mi * 32 + (r & 3) + 8 * (r >> 2) + 4 * kh] = p[r];
    }
  }
  __syncthreads();
  if (tid < 128)
    partials[(long)blockIdx.y * BT + m0 + tid] = rowsum[0][tid] + rowsum[1][tid];
}

// per-row: lse - x_y ; block partial sums
__global__ __launch_bounds__(256)
void row_reduce(const float* __restrict__ partials, const float* __restrict__ xy,
                const int* __restrict__ tgt, float* __restrict__ bsum,
                float* __restrict__ bcnt, int BT, int nCB) {
  int row = blockIdx.x * 256 + threadIdx.x;
  float S = 0.f;
  for (int b = 0; b < nCB; b++) S += partials[(long)b * BT + row];
  int t = tgt[row];
  bool valid = (t != -100);
  float pr = valid ? (logf(S) - xy[row]) : 0.f;
  float c = valid ? 1.f : 0.f;
  for (int off = 32; off; off >>= 1) {
    pr += __shfl_down(pr, off, 64);
    c += __shfl_down(c, off, 64);
  }
  __shared__ float sp[4], sc[4];
  if ((threadIdx.x & 63) == 0) {
    sp[threadIdx.x >> 6] = pr;
    sc[threadIdx.x >> 6] = c;
  }
  __syncthreads();
  if (threadIdx.x == 0) {
    bsum[blockIdx.x] = sp[0] + sp[1] + sp[2] + sp[3];
    bcnt[blockIdx.x] = sc[0] + sc[1] + sc[2] + sc[3];
  }
}

__global__ void finalize(const float* __restrict__ bsum, const float* __restrict__ bcnt,
                         float* __restrict__ out, int nb) {
  float s = 0.f, c = 0.f;
  for (int i = threadIdx.x; i < nb; i += 64) { s += bsum[i]; c += bcnt[i]; }
  for (int off = 32; off; off >>= 1) {
    s += __shfl_down(s, off, 64);
    c += __shfl_down(c, off, 64);
  }
  if (threadIdx.x == 0) out[0] = s / c;
}

extern "C" void kernel_launch(void* const* d_in, const int* in_sizes, int n_in,
                              void* d_out, int out_size, void* d_ws, size_t ws_size,
                              hipStream_t stream) {
  const float* x = (const float*)d_in[0];
  const int* tgt = (const int*)d_in[1];
  const float* w = (const float*)d_in[2];
  const float* bias = (const float*)d_in[3];
  float* out = (float*)d_out;

  const int BT = in_sizes[1];            // 4096
  const int V = in_sizes[3];             // 32000
  const int H = in_sizes[0] / BT;        // 1024
  const int nCB = V / 128;               // 250 column blocks

  char* ws = (char*)d_ws;
  const long wb_bytes = (long)V * H;     // fp8: 1 B/elem
  const long xb_bytes = (long)BT * H;
  char* Wb = ws;
  char* Xb = ws + wb_bytes;
  float* partials = (float*)(ws + wb_bytes + xb_bytes);
  float* xy = partials + (long)nCB * BT;
  float* bsum = xy + BT;
  float* bcnt = bsum + (BT / 256);

  cast_fp8_k<<<8192, 256, 0, stream>>>((const float4*)w, (uint4*)Wb, (long)V * H / 16);
  cast_fp8_k<<<1024, 256, 0, stream>>>((const float4*)x, (uint4*)Xb, (long)BT * H / 16);
  xy_k<<<BT, 256, 0, stream>>>(x, w, bias, tgt, xy, H, V);
  // grid.x = row-blocks (fast-varying) so consecutive blocks share the W tile in L2
  dim3 grid(BT / 128, nCB);
  gemm_sumexp<<<grid, 256, 0, stream>>>(Xb, Wb, bias, partials, H, BT);
  row_reduce<<<BT / 256, 256, 0, stream>>>(partials, xy, tgt, bsum, bcnt, BT, nCB);
  finalize<<<1, 64, 0, stream>>>(bsum, bcnt, out, BT / 256);
}